// Round 15
// baseline (83.013 us; speedup 1.0000x reference)
//
#include <hip/hip_runtime.h>

// Problem constants
#define BB   4096
#define MM   200
#define DD   100
#define NENT 5000
#define DP   128    // padded D (f16): Pr rows 256 B, PES rows 512 B

typedef _Float16 f16x2 __attribute__((ext_vector_type(2)));

#if defined(__has_builtin)
#if __has_builtin(__builtin_amdgcn_fdot2)
#define HAS_FDOT2 1
#endif
#endif

__device__ __forceinline__ f16x2 uh(unsigned u) { return __builtin_bit_cast(f16x2, u); }
__device__ __forceinline__ unsigned hu(f16x2 h) { return __builtin_bit_cast(unsigned, h); }

// ws layout (bytes):
//   Pr  : f16[5000][128] @ 0         = sym@W[:, :D]^T + bias  (d>=100 zero)
//   PES : f16[5000][256] @ 1,280,000 = [Pe 128 | sym 128] per entity (pads zero)

// ---------------------------------------------------------------------------
// Kernel A: project 5000 symbol rows through both halves of W, PADDED to 128.
// ---------------------------------------------------------------------------
__global__ __launch_bounds__(256) void precompute_kernel(
    const float* __restrict__ sym, const float* __restrict__ W,
    const float* __restrict__ wb, const float* __restrict__ gb,
    _Float16* __restrict__ Pr, _Float16* __restrict__ PES)
{
    __shared__ _Float16 Wt[200 * 102];
    const int tid = threadIdx.x;
    for (int j = tid; j < 20000; j += 256) {
        int d = j / 200, k = j % 200;
        Wt[k * 102 + d] = (_Float16)W[j];
    }
    __syncthreads();

    const int i = blockIdx.x * 256 + tid;
    if (i >= NENT * 64) return;
    const int e = i >> 6, dp = i & 63;
    const int d0 = 2 * dp;

    if (dp < 50) {
        const float* se = sym + e * DD;
        float pr0 = 0.f, pr1 = 0.f, pe0 = 0.f, pe1 = 0.f;
        for (int k = 0; k < 100; k++) {
            float a = se[k];
            f16x2 w01 = *(const f16x2*)&Wt[k * 102 + d0];
            f16x2 w23 = *(const f16x2*)&Wt[(k + 100) * 102 + d0];
            pr0 = fmaf(a, (float)w01.x, pr0);
            pr1 = fmaf(a, (float)w01.y, pr1);
            pe0 = fmaf(a, (float)w23.x, pe0);
            pe1 = fmaf(a, (float)w23.y, pe1);
        }
        pr0 += wb[d0]     + gb[d0];
        pr1 += wb[d0 + 1] + gb[d0 + 1];
        *(f16x2*)&Pr[e * DP + d0]            = f16x2{(_Float16)pr0, (_Float16)pr1};
        *(f16x2*)&PES[e * 2 * DP + d0]       = f16x2{(_Float16)pe0, (_Float16)pe1};
        *(f16x2*)&PES[e * 2 * DP + DP + d0]  = f16x2{(_Float16)se[d0], (_Float16)se[d0 + 1]};
    } else {
        f16x2 z = f16x2{(_Float16)0.f, (_Float16)0.f};
        *(f16x2*)&Pr[e * DP + d0]           = z;
        *(f16x2*)&PES[e * 2 * DP + d0]      = z;
        *(f16x2*)&PES[e * 2 * DP + DP + d0] = z;
    }
}

// ---------------------------------------------------------------------------
// Kernel B: one block per row; each m owned by a 4-lane QUAD. No barrier
// between x-compute and consume: logit quad-reduced via 2 shfl_xor, ev inline.
// Global quad id qid = t>>2 in [0,64); m = it*64 + qid (R14 BUG: used only
// (t>>2)&15, all waves computed the same m's). Lane q of a quad holds u32
// slots {q*4 + k + 16*i} of the 64-u32 row (dwordx4 at byte q*16 + i*64).
// One __syncthreads total (epilogue).
// ---------------------------------------------------------------------------
__global__ __launch_bounds__(256, 4) void main_kernel(
    const int*  __restrict__ conn, const int* __restrict__ target,
    const float* __restrict__ sym, const float* __restrict__ co,
    const _Float16* __restrict__ Pr, const _Float16* __restrict__ PES,
    const float* __restrict__ attn_w,
    const float* __restrict__ gate_w, const float* __restrict__ gate_wb,
    const float* __restrict__ gate_b,
    float* __restrict__ outp)
{
    __shared__ unsigned oa_l[4][64];
    __shared__ unsigned nb_l[4][64];
    __shared__ float    gs_l[4];

    const int t = threadIdx.x;
    const int row = blockIdx.x;
    const int q = t & 3;             // lane in quad
    const int qid = t >> 2;          // GLOBAL quad id in block [0,64)
    const int w = t >> 6;
    const int* cb = conn + row * (MM * 3);
    const int tgt = target[row * 2];

    // attn_w slice as f16 pairs for this lane's 16 u32 slots (pad -> 0)
    f16x2 aw_h[16];
    #pragma unroll
    for (int j = 0; j < 16; ++j) {
        int idx = q * 4 + (j & 3) + 16 * (j >> 2);
        int d0 = 2 * idx;
        float a0 = (d0 < DD) ? attn_w[d0] : 0.f;
        float a1 = (d0 + 1 < DD) ? attn_w[d0 + 1] : 0.f;
        aw_h[j] = f16x2{(_Float16)a0, (_Float16)a1};
    }

    // prefetch per-m metadata (m = it*64 + qid): rel, ent, co
    int rr[4], ee[4];
    float cov[4];
    #pragma unroll
    for (int it = 0; it < 4; ++it) {
        int m = it * 64 + qid;
        if (m < MM) {
            rr[it] = cb[m * 3 + 1];
            ee[it] = cb[m * 3 + 2];
            cov[it] = co[(long)ee[it] * NENT + tgt];   // quad-uniform addr
        }
    }

    const _Float16 slope = (_Float16)0.01f;
    f16x2 oa[16], nb[16];
    #pragma unroll
    for (int j = 0; j < 16; ++j) {
        oa[j] = f16x2{(_Float16)0.f, (_Float16)0.f};
        nb[j] = oa[j];
    }
    float gsum = 0.f;

    #pragma unroll
    for (int it = 0; it < 4; ++it) {
        int m = it * 64 + qid;
        if (m < MM) {
            const char* prb = (const char*)Pr + ((long)rr[it] << 8);
            const char* peb = (const char*)PES + ((long)ee[it] << 9);
            unsigned xr[16];
            float lp = 0.f;
            #pragma unroll
            for (int i = 0; i < 4; ++i) {
                uint4 a4 = *(const uint4*)(prb + q * 16 + i * 64);
                uint4 b4 = *(const uint4*)(peb + q * 16 + i * 64);
                unsigned av[4] = {a4.x, a4.y, a4.z, a4.w};
                unsigned bv[4] = {b4.x, b4.y, b4.z, b4.w};
                #pragma unroll
                for (int k = 0; k < 4; ++k) {
                    f16x2 x = uh(av[k]) + uh(bv[k]);
                    x = __builtin_elementwise_max(x, x * slope);   // leaky relu
                    xr[i * 4 + k] = hu(x);
#ifdef HAS_FDOT2
                    lp = __builtin_amdgcn_fdot2(x, aw_h[i * 4 + k], lp, false);
#else
                    lp += (float)x.x * (float)aw_h[i * 4 + k].x
                        + (float)x.y * (float)aw_h[i * 4 + k].y;
#endif
                }
            }
            // quad reduce of logit (no barrier, no LDS)
            lp += __shfl_xor(lp, 1);
            lp += __shfl_xor(lp, 2);
            float ev = __expf(lp);                   // no max: logits tiny
            gsum += ev;
            f16x2 evh = f16x2{(_Float16)ev, (_Float16)ev};
            f16x2 coh = f16x2{(_Float16)cov[it], (_Float16)cov[it]};
            // Sy slice (PES + 256 B) + accumulate
            #pragma unroll
            for (int i = 0; i < 4; ++i) {
                uint4 s4 = *(const uint4*)(peb + 256 + q * 16 + i * 64);
                unsigned sv[4] = {s4.x, s4.y, s4.z, s4.w};
                #pragma unroll
                for (int k = 0; k < 4; ++k) {
                    int j = i * 4 + k;
                    oa[j] = evh * uh(xr[j]) + oa[j];
                    nb[j] = coh * uh(sv[k]) + nb[j];
                }
            }
        }
    }

    // cross-quad butterfly within wave (strides 4..32; lane parity q kept)
    #pragma unroll
    for (int st = 4; st <= 32; st <<= 1) {
        gsum += __shfl_xor(gsum, st);
        #pragma unroll
        for (int j = 0; j < 16; ++j) {
            oa[j] = oa[j] + uh((unsigned)__shfl_xor((int)hu(oa[j]), st));
            nb[j] = nb[j] + uh((unsigned)__shfl_xor((int)hu(nb[j]), st));
        }
    }
    // lanes 0-3 of each wave hold wave totals; write to LDS
    if ((t & 63) < 4) {
        #pragma unroll
        for (int j = 0; j < 16; ++j) {
            int idx = q * 4 + (j & 3) + 16 * (j >> 2);
            oa_l[w][idx] = hu(oa[j]);
            nb_l[w][idx] = hu(nb[j]);
        }
        if (q == 0) gs_l[w] = gsum;
    }
    __syncthreads();                                 // only barrier

    if (t < 64) {
        f16x2 oau = uh(oa_l[0][t]) + uh(oa_l[1][t]);
        oau = oau + uh(oa_l[2][t]);
        oau = oau + uh(oa_l[3][t]);
        f16x2 nbu = uh(nb_l[0][t]) + uh(nb_l[1][t]);
        nbu = nbu + uh(nb_l[2][t]);
        nbu = nbu + uh(nb_l[3][t]);
        float gst = (gs_l[0] + gs_l[1]) + (gs_l[2] + gs_l[3]);
        float inv = 1.f / gst;
        float o0 = (float)oau.x * inv, o1 = (float)oau.y * inv;
        float n0 = (float)nbu.x,       n1 = (float)nbu.y;
        const int d0 = 2 * t;

        // gate dot over wave 0 (d >= 100 contributes 0)
        float p = (t < DD / 2) ? o0 * gate_w[d0] + o1 * gate_w[d0 + 1] : 0.f;
        #pragma unroll
        for (int off = 32; off >= 1; off >>= 1) p += __shfl_xor(p, off);
        float gt = 1.f / (1.f + __expf(-(p + gate_wb[0] + gate_b[0])));

        if (t < DD / 2) {
            int s_self = cb[0];
            const float* sv = sym + (long)s_self * DD + d0;
            float* op = outp + (long)row * DD + d0;
            op[0] = o0 * gt + sv[0] * (1.f - gt) + n0;
            op[1] = o1 * gt + sv[1] * (1.f - gt) + n1;
        }
    }
}

extern "C" void kernel_launch(void* const* d_in, const int* in_sizes, int n_in,
                              void* d_out, int out_size, void* d_ws, size_t ws_size,
                              hipStream_t stream) {
    const int*   conn    = (const int*)  d_in[0];
    const int*   target  = (const int*)  d_in[1];
    const float* sym     = (const float*)d_in[2];
    const float* co      = (const float*)d_in[3];
    const float* W       = (const float*)d_in[4];
    const float* wb      = (const float*)d_in[5];
    const float* gb      = (const float*)d_in[6];
    const float* attn_w  = (const float*)d_in[7];
    // d_in[8] = attn_w_bias: cancels in softmax, unused
    const float* gate_w  = (const float*)d_in[9];
    const float* gate_wb = (const float*)d_in[10];
    const float* gate_b  = (const float*)d_in[11];

    _Float16* Pr  = (_Float16*)d_ws;
    _Float16* PES = (_Float16*)((char*)d_ws + 1280000);

    precompute_kernel<<<(NENT * 64 + 255) / 256, 256, 0, stream>>>(
        sym, W, wb, gb, Pr, PES);

    main_kernel<<<BB, 256, 0, stream>>>(
        conn, target, sym, co, Pr, PES,
        attn_w, gate_w, gate_wb, gate_b, (float*)d_out);
}